// Round 1
// baseline (383.076 us; speedup 1.0000x reference)
//
#include <hip/hip_runtime.h>
#include <hip/hip_bf16.h>

typedef __bf16 bf16x8 __attribute__((ext_vector_type(8)));
typedef __bf16 bf16x4 __attribute__((ext_vector_type(4)));
typedef float  f32x4  __attribute__((ext_vector_type(4)));

#define NROW 4096
#define XSTR 384
#define DHEAD 128
#define QBLK 64
#define KVB 64

__launch_bounds__(256, 2)
__global__ void attn_fwd_kernel(const float* __restrict__ x, float* __restrict__ out) {
    const int b   = blockIdx.y;
    const int t0  = blockIdx.x * QBLK;
    const int tid = threadIdx.x;
    const int w   = tid >> 6;   // wave id 0..3
    const int l   = tid & 63;   // lane
    const int lr  = l & 15;     // row/col selector within fragment
    const int lg  = l >> 4;     // 16-lane group 0..3

    // K_eff tile [s][c] padded: row stride 136 bf16 = 272B -> lanes at 4-bank step (2-way, free)
    __shared__ __bf16 Kt[KVB][136];
    // V transposed [c][s] padded: row stride 72 bf16 = 144B
    __shared__ __bf16 Vt[DHEAD][72];
    // per-wave P tile [row][s]
    __shared__ __bf16 Pl[4][16][72];

    const float* xb = x + (size_t)b * NROW * XSTR;

    // ---- Q fragments (the k-slice of x, cols 128..255), rows t0 + w*16 + lr ----
    // A-frag layout for mfma_f32_16x16x32_bf16: row = lane&15, k = (lane>>4)*8 + e
    bf16x8 qf[4];
    {
        const float* qrow = xb + (size_t)(t0 + w * 16 + lr) * XSTR + DHEAD;
        #pragma unroll
        for (int kc = 0; kc < 4; ++kc) {
            const float4 f0 = *(const float4*)(qrow + kc * 32 + lg * 8);
            const float4 f1 = *(const float4*)(qrow + kc * 32 + lg * 8 + 4);
            bf16x8 v;
            v[0] = (__bf16)f0.x; v[1] = (__bf16)f0.y; v[2] = (__bf16)f0.z; v[3] = (__bf16)f0.w;
            v[4] = (__bf16)f1.x; v[5] = (__bf16)f1.y; v[6] = (__bf16)f1.z; v[7] = (__bf16)f1.w;
            qf[kc] = v;
        }
    }

    f32x4 oacc[8];
    #pragma unroll
    for (int i = 0; i < 8; ++i) { f32x4 z = {0.f, 0.f, 0.f, 0.f}; oacc[i] = z; }
    float mrow[4], lrow[4];
    #pragma unroll
    for (int r = 0; r < 4; ++r) { mrow[r] = -1e30f; lrow[r] = 0.f; }

    // p = exp2((s_raw - m_raw) * C) with C = (1/sqrt(128)) * log2(e)
    const float C = 0.08838834764831845f * 1.44269504088896340f;

    for (int s0 = 0; s0 < NROW; s0 += KVB) {
        // ---- stage K_eff (q-slice, cols 0..127): 64x128 fp32 -> bf16 ----
        #pragma unroll
        for (int i = 0; i < 8; ++i) {
            int chunk = tid + i * 256;          // 0..2047
            int row   = chunk >> 5;             // 0..63
            int c     = (chunk & 31) << 2;      // 0..124
            float4 f = *(const float4*)(xb + (size_t)(s0 + row) * XSTR + c);
            bf16x4 v;
            v[0] = (__bf16)f.x; v[1] = (__bf16)f.y; v[2] = (__bf16)f.z; v[3] = (__bf16)f.w;
            *(bf16x4*)&Kt[row][c] = v;
        }
        // ---- stage V (v-slice, cols 256..383) transposed: Vt[c][s] ----
        #pragma unroll
        for (int i = 0; i < 2; ++i) {
            int blk = tid + i * 256;            // 0..511
            int sb  = (blk & 15) << 2;          // 0..60
            int cb  = (blk >> 4) << 2;          // 0..124
            float buf[4][4];
            #pragma unroll
            for (int r = 0; r < 4; ++r) {
                float4 f = *(const float4*)(xb + (size_t)(s0 + sb + r) * XSTR + 256 + cb);
                buf[r][0] = f.x; buf[r][1] = f.y; buf[r][2] = f.z; buf[r][3] = f.w;
            }
            #pragma unroll
            for (int cc = 0; cc < 4; ++cc) {
                bf16x4 v;
                v[0] = (__bf16)buf[0][cc]; v[1] = (__bf16)buf[1][cc];
                v[2] = (__bf16)buf[2][cc]; v[3] = (__bf16)buf[3][cc];
                *(bf16x4*)&Vt[cb + cc][sb] = v;
            }
        }
        __syncthreads();

        // ---- QK^T: D[t][s] = A(Q_eff) x B(K_eff^T), 4 s-tiles x 4 k-chunks ----
        f32x4 sacc[4];
        #pragma unroll
        for (int st = 0; st < 4; ++st) { f32x4 z = {0.f, 0.f, 0.f, 0.f}; sacc[st] = z; }
        #pragma unroll
        for (int kc = 0; kc < 4; ++kc) {
            #pragma unroll
            for (int st = 0; st < 4; ++st) {
                // B-frag: col s = st*16 + (lane&15), k = c = kc*32 + (lane>>4)*8 + e
                bf16x8 bf = *(const bf16x8*)&Kt[st * 16 + lr][kc * 32 + lg * 8];
                sacc[st] = __builtin_amdgcn_mfma_f32_16x16x32_bf16(qf[kc], bf, sacc[st], 0, 0, 0);
            }
        }

        // ---- online softmax (rows = lg*4 + r, cols spread over lanes of the 16-group) ----
        float rmax[4], psum[4], alpha[4];
        #pragma unroll
        for (int r = 0; r < 4; ++r)
            rmax[r] = fmaxf(fmaxf(sacc[0][r], sacc[1][r]), fmaxf(sacc[2][r], sacc[3][r]));
        #pragma unroll
        for (int mk = 1; mk <= 8; mk <<= 1) {
            #pragma unroll
            for (int r = 0; r < 4; ++r) rmax[r] = fmaxf(rmax[r], __shfl_xor(rmax[r], mk));
        }
        #pragma unroll
        for (int r = 0; r < 4; ++r) {
            float mnew = fmaxf(mrow[r], rmax[r]);
            alpha[r]   = __builtin_amdgcn_exp2f((mrow[r] - mnew) * C);
            mrow[r]    = mnew;
            psum[r]    = 0.f;
        }
        #pragma unroll
        for (int st = 0; st < 4; ++st) {
            #pragma unroll
            for (int r = 0; r < 4; ++r) {
                float p = __builtin_amdgcn_exp2f((sacc[st][r] - mrow[r]) * C);
                psum[r] += p;
                Pl[w][lg * 4 + r][st * 16 + lr] = (__bf16)p;
            }
        }
        #pragma unroll
        for (int mk = 1; mk <= 8; mk <<= 1) {
            #pragma unroll
            for (int r = 0; r < 4; ++r) psum[r] += __shfl_xor(psum[r], mk);
        }
        #pragma unroll
        for (int r = 0; r < 4; ++r) lrow[r] = lrow[r] * alpha[r] + psum[r];
        #pragma unroll
        for (int ct = 0; ct < 8; ++ct) {
            #pragma unroll
            for (int r = 0; r < 4; ++r) oacc[ct][r] *= alpha[r];
        }

        // ---- PV: out[t][c] += P[t][s] * V[s][c] ----
        // A-frag from Pl: row t = lane&15, k = s = (lane>>4)*8 + e (+32 for second chunk)
        bf16x8 pa0 = *(const bf16x8*)&Pl[w][lr][lg * 8];
        bf16x8 pa1 = *(const bf16x8*)&Pl[w][lr][32 + lg * 8];
        #pragma unroll
        for (int ct = 0; ct < 8; ++ct) {
            // B-frag: col c = ct*16 + (lane&15), k = s -> Vt[c][s] contiguous in s
            bf16x8 b0 = *(const bf16x8*)&Vt[ct * 16 + lr][lg * 8];
            bf16x8 b1 = *(const bf16x8*)&Vt[ct * 16 + lr][32 + lg * 8];
            oacc[ct] = __builtin_amdgcn_mfma_f32_16x16x32_bf16(pa0, b0, oacc[ct], 0, 0, 0);
            oacc[ct] = __builtin_amdgcn_mfma_f32_16x16x32_bf16(pa1, b1, oacc[ct], 0, 0, 0);
        }
        __syncthreads();
    }

    // ---- epilogue: out[t][c] = O[t][c] / l[t] ----
    float inv[4];
    #pragma unroll
    for (int r = 0; r < 4; ++r) inv[r] = 1.f / lrow[r];
    float* orow = out + ((size_t)b * NROW + t0 + w * 16) * DHEAD;
    #pragma unroll
    for (int ct = 0; ct < 8; ++ct) {
        #pragma unroll
        for (int r = 0; r < 4; ++r) {
            orow[(size_t)(lg * 4 + r) * DHEAD + ct * 16 + lr] = oacc[ct][r] * inv[r];
        }
    }
}

extern "C" void kernel_launch(void* const* d_in, const int* in_sizes, int n_in,
                              void* d_out, int out_size, void* d_ws, size_t ws_size,
                              hipStream_t stream) {
    const float* x = (const float*)d_in[0];
    float* out = (float*)d_out;
    dim3 grid(NROW / QBLK, 4);
    attn_fwd_kernel<<<grid, 256, 0, stream>>>(x, out);
}

// Round 4
// 212.378 us; speedup vs baseline: 1.8037x; 1.8037x over previous
//
#include <hip/hip_runtime.h>
#include <hip/hip_bf16.h>

typedef __bf16 bf16x8 __attribute__((ext_vector_type(8)));
typedef __bf16 bf16x4 __attribute__((ext_vector_type(4)));
typedef float  f32x4  __attribute__((ext_vector_type(4)));

#define NROW 4096
#define XSTR 384
#define DHEAD 128
#define QBLK 64
#define KVB 128
#define NIT (NROW / KVB)

__launch_bounds__(512, 2)
__global__ void attn_fwd_kernel(const float* __restrict__ x, float* __restrict__ out) {
    const int b   = blockIdx.y;
    const int t0  = blockIdx.x * QBLK;
    const int tid = threadIdx.x;
    const int w   = tid >> 6;   // wave 0..7
    const int wq  = w & 3;      // q-row group (16 rows)
    const int kvh = w >> 2;     // KV half: 0 -> s [0,64), 1 -> s [64,128) of staged tile
    const int l   = tid & 63;
    const int lr  = l & 15;
    const int lg  = l >> 4;

    // stride 132 bf16 = 264B = 66 dwords -> bank step 2/row: 16 rows hit 16 distinct banks
    __shared__ union {
        struct { __bf16 Kt[128][132]; __bf16 Vt[128][132]; } t;   // Kt[s][c], Vt[c][s]
        struct { float O[4][16][128]; float m[4][16]; float lsum[4][16]; } mrg;
    } U;
    __shared__ __bf16 Pl[8][16][68];   // per-wave P tile, stride 68 -> bank step 2

    const float* xb = x + (size_t)b * NROW * XSTR;

    // ---- Q fragments (k-slice cols 128..255), rows t0 + wq*16 + lr ----
    bf16x8 qf[4];
    {
        const float* qrow = xb + (size_t)(t0 + wq * 16 + lr) * XSTR + DHEAD;
        #pragma unroll
        for (int kc = 0; kc < 4; ++kc) {
            const float4 f0 = *(const float4*)(qrow + kc * 32 + lg * 8);
            const float4 f1 = *(const float4*)(qrow + kc * 32 + lg * 8 + 4);
            bf16x8 v;
            v[0] = (__bf16)f0.x; v[1] = (__bf16)f0.y; v[2] = (__bf16)f0.z; v[3] = (__bf16)f0.w;
            v[4] = (__bf16)f1.x; v[5] = (__bf16)f1.y; v[6] = (__bf16)f1.z; v[7] = (__bf16)f1.w;
            qf[kc] = v;
        }
    }

    f32x4 oacc[8];
    #pragma unroll
    for (int i = 0; i < 8; ++i) { f32x4 z = {0.f, 0.f, 0.f, 0.f}; oacc[i] = z; }
    float mrow[4], lrow[4];
    #pragma unroll
    for (int r = 0; r < 4; ++r) { mrow[r] = -1e30f; lrow[r] = 0.f; }

    const float C = 0.08838834764831845f * 1.44269504088896340f; // 1/sqrt(128)*log2(e)

    const int krow = tid >> 5;          // 0..15
    const int kcol = (tid & 31) << 2;   // 0..124

    float4 pk[8], pv[8];

    auto prefetch = [&](int S0) {
        #pragma unroll
        for (int i = 0; i < 8; ++i)
            pk[i] = *(const float4*)(xb + (size_t)(S0 + krow + i * 16) * XSTR + kcol);
        #pragma unroll
        for (int i2 = 0; i2 < 2; ++i2) {
            const int cb = (krow + i2 * 16) << 2;
            #pragma unroll
            for (int r = 0; r < 4; ++r)
                pv[i2 * 4 + r] = *(const float4*)(xb + (size_t)(S0 + kcol + r) * XSTR + 256 + cb);
        }
    };
    auto write_lds = [&]() {
        #pragma unroll
        for (int i = 0; i < 8; ++i) {
            const float* f = (const float*)&pk[i];
            bf16x4 v;
            v[0] = (__bf16)f[0]; v[1] = (__bf16)f[1]; v[2] = (__bf16)f[2]; v[3] = (__bf16)f[3];
            *(bf16x4*)&U.t.Kt[krow + i * 16][kcol] = v;
        }
        #pragma unroll
        for (int i2 = 0; i2 < 2; ++i2) {
            const int cb = (krow + i2 * 16) << 2;
            #pragma unroll
            for (int cc = 0; cc < 4; ++cc) {
                bf16x4 v;
                #pragma unroll
                for (int r = 0; r < 4; ++r)
                    v[r] = (__bf16)((const float*)&pv[i2 * 4 + r])[cc];
                *(bf16x4*)&U.t.Vt[cb + cc][kcol] = v;   // Vt[c][s], s = kcol..kcol+3
            }
        }
    };

    prefetch(0);
    write_lds();
    __syncthreads();

    for (int it = 0; it < NIT; ++it) {
        if (it + 1 < NIT) prefetch((it + 1) * KVB);   // issue loads; hide under compute

        const int sb = kvh * 64;

        // ---- QK^T over this wave's 64-col KV half ----
        f32x4 sacc[4];
        #pragma unroll
        for (int st = 0; st < 4; ++st) { f32x4 z = {0.f, 0.f, 0.f, 0.f}; sacc[st] = z; }
        #pragma unroll
        for (int kc = 0; kc < 4; ++kc) {
            #pragma unroll
            for (int st = 0; st < 4; ++st) {
                bf16x8 bf = *(const bf16x8*)&U.t.Kt[sb + st * 16 + lr][kc * 32 + lg * 8];
                sacc[st] = __builtin_amdgcn_mfma_f32_16x16x32_bf16(qf[kc], bf, sacc[st], 0, 0, 0);
            }
        }

        // ---- online softmax (per-wave, over its private s subset) ----
        float rmax[4], psum[4], alpha[4];
        #pragma unroll
        for (int r = 0; r < 4; ++r)
            rmax[r] = fmaxf(fmaxf(sacc[0][r], sacc[1][r]), fmaxf(sacc[2][r], sacc[3][r]));
        #pragma unroll
        for (int mk = 1; mk <= 8; mk <<= 1) {
            #pragma unroll
            for (int r = 0; r < 4; ++r) rmax[r] = fmaxf(rmax[r], __shfl_xor(rmax[r], mk));
        }
        #pragma unroll
        for (int r = 0; r < 4; ++r) {
            float mnew = fmaxf(mrow[r], rmax[r]);
            alpha[r]   = __builtin_amdgcn_exp2f((mrow[r] - mnew) * C);
            mrow[r]    = mnew;
            psum[r]    = 0.f;
        }
        #pragma unroll
        for (int st = 0; st < 4; ++st) {
            #pragma unroll
            for (int r = 0; r < 4; ++r) {
                float p = __builtin_amdgcn_exp2f((sacc[st][r] - mrow[r]) * C);
                psum[r] += p;
                Pl[w][lg * 4 + r][st * 16 + lr] = (__bf16)p;
            }
        }
        #pragma unroll
        for (int mk = 1; mk <= 8; mk <<= 1) {
            #pragma unroll
            for (int r = 0; r < 4; ++r) psum[r] += __shfl_xor(psum[r], mk);
        }
        #pragma unroll
        for (int r = 0; r < 4; ++r) lrow[r] = lrow[r] * alpha[r] + psum[r];
        #pragma unroll
        for (int ct = 0; ct < 8; ++ct) {
            #pragma unroll
            for (int r = 0; r < 4; ++r) oacc[ct][r] *= alpha[r];
        }

        // ---- PV over this wave's KV half ----
        bf16x8 pa0 = *(const bf16x8*)&Pl[w][lr][lg * 8];
        bf16x8 pa1 = *(const bf16x8*)&Pl[w][lr][32 + lg * 8];
        #pragma unroll
        for (int ct = 0; ct < 8; ++ct) {
            bf16x8 b0 = *(const bf16x8*)&U.t.Vt[ct * 16 + lr][sb + lg * 8];
            bf16x8 b1 = *(const bf16x8*)&U.t.Vt[ct * 16 + lr][sb + 32 + lg * 8];
            oacc[ct] = __builtin_amdgcn_mfma_f32_16x16x32_bf16(pa0, b0, oacc[ct], 0, 0, 0);
            oacc[ct] = __builtin_amdgcn_mfma_f32_16x16x32_bf16(pa1, b1, oacc[ct], 0, 0, 0);
        }
        __syncthreads();                       // all waves done reading Kt/Vt
        if (it + 1 < NIT) { write_lds(); __syncthreads(); }
    }

    // ---- merge the two KV-half partials (exact log-sum-exp combine) ----
    if (kvh == 1) {
        #pragma unroll
        for (int ct = 0; ct < 8; ++ct) {
            #pragma unroll
            for (int r = 0; r < 4; ++r)
                U.mrg.O[wq][lg * 4 + r][ct * 16 + lr] = oacc[ct][r];
        }
        if (lr == 0) {
            #pragma unroll
            for (int r = 0; r < 4; ++r) {
                U.mrg.m[wq][lg * 4 + r]    = mrow[r];
                U.mrg.lsum[wq][lg * 4 + r] = lrow[r];
            }
        }
    }
    __syncthreads();
    if (kvh == 0) {
        float* orow = out + ((size_t)b * NROW + t0 + wq * 16) * DHEAD;
        #pragma unroll
        for (int r = 0; r < 4; ++r) {
            const float m2 = U.mrg.m[wq][lg * 4 + r];
            const float l2 = U.mrg.lsum[wq][lg * 4 + r];
            const float mm = fmaxf(mrow[r], m2);
            const float a1 = __builtin_amdgcn_exp2f((mrow[r] - mm) * C);
            const float a2 = __builtin_amdgcn_exp2f((m2 - mm) * C);
            const float inv = 1.f / (lrow[r] * a1 + l2 * a2);
            #pragma unroll
            for (int ct = 0; ct < 8; ++ct) {
                const float o2 = U.mrg.O[wq][lg * 4 + r][ct * 16 + lr];
                orow[(size_t)(lg * 4 + r) * DHEAD + ct * 16 + lr] =
                    (oacc[ct][r] * a1 + o2 * a2) * inv;
            }
        }
    }
}

extern "C" void kernel_launch(void* const* d_in, const int* in_sizes, int n_in,
                              void* d_out, int out_size, void* d_ws, size_t ws_size,
                              hipStream_t stream) {
    const float* x = (const float*)d_in[0];
    float* out = (float*)d_out;
    dim3 grid(NROW / QBLK, 4);
    attn_fwd_kernel<<<grid, 512, 0, stream>>>(x, out);
}